// Round 1
// baseline (141.672 us; speedup 1.0000x reference)
//
#include <hip/hip_runtime.h>

#define NB   1024
#define NL   4096
#define TPB  256
#define QSTEP 1024               // steps per block (quarter row)
#define SPT  4                   // steps per thread

// ws float-offsets: partials only (prep fused into main)
#define WS_PART 16640            // partials: [row*4+q]*12, 12 floats each

typedef float v2f __attribute__((ext_vector_type(2)));

__device__ __forceinline__ float fast_rcp(float x) { return __builtin_amdgcn_rcpf(x); }
__device__ __forceinline__ float fexp2(float x) { return __builtin_amdgcn_exp2f(x); }  // 2^x
__device__ __forceinline__ float flog2(float x) { return __builtin_amdgcn_logf(x); }   // log2(x)

#define L2E 1.44269504088896340736f
#define LN2 0.69314718055994530942f

// Even part of softplus in log2 domain: F(x) = log2(1+2^x) - x/2 = F(-x).
// Cubic in s=x^2; max |err| ~1e-3 on |x|<=4.
#define SP_C0 1.0f
#define SP_C1 0.0864667f
#define SP_C2 (-0.0015685f)
#define SP_C3 2.5763e-5f

// ---------------- kernel A: main scan-as-reduction (prep fused) ----------
// block = row*4 + q ; 256 threads x 4 steps = 1024 steps per block.
// Coalesced global->LDS staging with XOR bank swizzle (float4 index
// w -> w ^ ((w>>3)&7)): writes 2-way/free, strided reads conflict-free.
// Weight prep (formerly separate kernel) is wave-uniform scalar work that
// overlaps the staging loads. MLP evaluated 2 steps at a time packed in
// v2f -> v_pk_fma_f32 (halves the softplus-chain instruction count).
__global__ void __launch_bounds__(TPB) onenet_main(
    const float* __restrict__ X,   const float* __restrict__ SC,
    const float* __restrict__ pW1, const float* __restrict__ pb1,
    const float* __restrict__ pW2, const float* __restrict__ pb2,
    const float* __restrict__ rW1, const float* __restrict__ rb1,
    const float* __restrict__ rW2, const float* __restrict__ rb2,
    float* __restrict__ ws)
{
    __shared__ float4 tile[TPB * 5];          // 20 KB staging
    __shared__ float  red[TPB / 64][9];

    const int bid  = blockIdx.x;
    const int row  = bid >> 2;
    const int q    = bid & 3;
    const int tid  = threadIdx.x;
    const int lane = tid & 63;
    const int w    = tid >> 6;

    // ---- coalesced staging: quarter-row (1024 steps, 20 KB) ----
    const float* Xq = X + ((size_t)row * NL + (size_t)q * QSTEP) * 5;
    {
        const float4* gq = (const float4*)Xq;
#pragma unroll
        for (int k = 0; k < 5; ++k) {
            int widx = tid + TPB * k;
            int sw   = widx ^ ((widx >> 3) & 7);
            tile[sw] = gq[widx];
        }
    }

    // ---- uniform weight prep (scalar loads/ALU, overlaps staging) ----
    const float sc0 = SC[row * 3 + 0];
    const float sc1 = SC[row * 3 + 1];
    const float sc2 = SC[row * 3 + 2];

    float W1S[10], W1T[10], BASE[10];
    float VR1[10], VRC[10], VOC[10], VMH[10], VKH[10];
#pragma unroll
    for (int j = 0; j < 10; ++j) {
        W1S[j]  = L2E * pW1[j];
        W1T[j]  = L2E * pW1[10 + j];
        BASE[j] = L2E * fmaf(sc0, pW1[20 + j],
                        fmaf(sc1, pW1[30 + j],
                        fmaf(sc2, pW1[40 + j], pb1[j])));
    }
    const float UBLB0 = 0.015f, UBLB1 = 0.045f, UBLB2 = 0.9f,
                UBLB3 = 0.055f, UBLB4 = 0.023f;
    const float KC = LN2 * 0.0025f;
#pragma unroll
    for (int j = 0; j < 10; ++j) {
        VR1[j] = KC * UBLB0 * pW2[5 * j + 0];
        VRC[j] = KC * UBLB1 * pW2[5 * j + 1];
        VOC[j] = KC * UBLB2 * pW2[5 * j + 2];
        VMH[j] = KC * UBLB3 * pW2[5 * j + 3];
        VKH[j] = KC * UBLB4 * pW2[5 * j + 4];
    }
    const float A0 = 0.005f + UBLB0 * fmaf(0.0025f, pb2[0], 0.5f);
    const float A1 = 0.025f + UBLB1 * fmaf(0.0025f, pb2[1], 0.5f);
    const float A2 = 0.1f   + UBLB2 * fmaf(0.0025f, pb2[2], 0.5f);
    const float A3 = 0.0f   + UBLB3 * fmaf(0.0025f, pb2[3], 0.5f);
    const float A4 = 0.002f + UBLB4 * fmaf(0.0025f, pb2[4], 0.5f);

    // r-net (one-off, exact transcendentals), only needed by q==0 blocks
    float Rs = 0.f;
    if (q == 0) {
        const float* x0 = X + (size_t)row * NL * 5;
        float T0 = x0[2], SOC0 = x0[4];
        float u = rb1[0];
        u = fmaf(SOC0, rW1[0], u);
        u = fmaf(T0,   rW1[1], u);
        u = fmaf(sc0,  rW1[2], u);
        u = fmaf(sc1,  rW1[3], u);
        u = fmaf(sc2,  rW1[4], u);
        float sp = LN2 * flog2(1.0f + fexp2(L2E * u));
        Rs = sc2 * (1.0f + fmaf(sp, rW2[0], rb2[0]));
    }

    __syncthreads();                          // staging visible

    // ---- conflict-free LDS reads: this thread's 4 steps (20 floats) ----
    float f[20];
#pragma unroll
    for (int j = 0; j < 5; ++j) {
        int widx = 5 * tid + j;
        int sw   = widx ^ ((widx >> 3) & 7);
        *(float4*)&f[4 * j] = tile[sw];
    }
    // t of the step after this thread's last
    float tn;
    {
        int wn  = 5 * ((tid + 1) & (TPB - 1));   // clamped for tid==255
        int swn = wn ^ ((wn >> 3) & 7);
        float tl = tile[swn].x;
        if (tid < TPB - 1)      tn = tl;
        else if (q == 3)        tn = f[15];      // dt=0 -> identity at step 4095
        else                    tn = Xq[QSTEP * 5];
    }

    v2f a = {1.f, 1.f}, b = {0.f, 0.f}, cS = {0.f, 0.f}, dS = {0.f, 0.f};
    v2f oaccv = {0.f, 0.f};
    float OCV0 = 0.f, I0 = 0.f;

#pragma unroll
    for (int ip = 0; ip < 2; ++ip) {          // two step-pairs: (0,1),(2,3)
        const int i0 = 2 * ip, i1 = 2 * ip + 1;
        v2f SSv = { f[5 * i0 + 4], f[5 * i1 + 4] };
        v2f Ttv = { f[5 * i0 + 2], f[5 * i1 + 2] };
        v2f Iv  = { f[5 * i0 + 1], f[5 * i1 + 1] };
        float tnx1 = (i1 < SPT - 1) ? f[5 * i1 + 5] : tn;
        v2f dtv = { f[5 * i1 + 0] - f[5 * i0 + 0], tnx1 - f[5 * i1 + 0] };
        v2f invv = { fast_rcp(Iv.x), fast_rcp(Iv.y) };

        v2f tR1 = {A0, A0}, tRC = {A1, A1}, tOC = {A2, A2},
            tMH = {A3, A3}, tKH = {A4, A4};
#pragma unroll
        for (int j = 0; j < 10; ++j) {
            v2f pre = SSv * W1S[j] + Ttv * W1T[j] + BASE[j];
            v2f s   = pre * pre;
            v2f p   = s * SP_C3 + SP_C2;
            p = s * p + SP_C1;
            p = s * p + SP_C0;
            v2f lam = pre * 0.5f + p;          // softplus2(pre), poly approx
            tR1 += lam * VR1[j];
            tRC += lam * VRC[j];
            tOC += lam * VOC[j];
            tMH += lam * VMH[j];
            tKH += lam * VKH[j];
        }
        oaccv += tOC * invv;                   // negated at the end
        if (ip == 0) { OCV0 = tOC.x; I0 = Iv.x; }

        // packed build of per-step affine pieces
        v2f g  = dtv * tKH * Iv;
        v2f hh = dtv * tRC;
        v2f bx = g * tMH;
        v2f by = hh * tR1 * Iv;

        // sequential application, step i0 then i1 (S-accum with pre-step U)
        {
            v2f sv = {1.f + g.x, 1.f - hh.x};
            v2f bv = {bx.x, by.x};
            v2f iv = {invv.x, invv.x};
            cS = iv * a + cS;
            dS = iv * b + dS;
            b  = sv * b + bv;
            a  = sv * a;
        }
        {
            v2f sv = {1.f + g.y, 1.f - hh.y};
            v2f bv = {bx.y, by.y};
            v2f iv = {invv.y, invv.y};
            cS = iv * a + cS;
            dS = iv * b + dS;
            b  = sv * b + bv;
            a  = sv * a;
        }
    }
    float oacc = -(oaccv.x + oaccv.y);

    // wave-level order-preserving tree reduce (L=self, R=lane+off)
#pragma unroll
    for (int off = 1; off < 64; off <<= 1) {
        v2f a2, b2, c2, d2;
        a2.x = __shfl_down(a.x, off);  a2.y = __shfl_down(a.y, off);
        b2.x = __shfl_down(b.x, off);  b2.y = __shfl_down(b.y, off);
        c2.x = __shfl_down(cS.x, off); c2.y = __shfl_down(cS.y, off);
        d2.x = __shfl_down(dS.x, off); d2.y = __shfl_down(dS.y, off);
        float o2 = __shfl_down(oacc, off);
        v2f nb = a2 * b + b2;
        v2f nc = c2 * a + cS;
        v2f nd = (dS + d2) + c2 * b;
        a = a2 * a; b = nb; cS = nc; dS = nd;
        oacc += o2;
    }

    if (lane == 0) {
        red[w][0] = a.x;  red[w][1] = a.y;
        red[w][2] = b.x;  red[w][3] = b.y;
        red[w][4] = cS.x; red[w][5] = cS.y;
        red[w][6] = dS.x; red[w][7] = dS.y;
        red[w][8] = oacc;
    }
    __syncthreads();

    if (tid == 0) {
#pragma unroll
        for (int k = 1; k < TPB / 64; ++k) {
            v2f ak, bk, ck, dk;
            ak.x = red[k][0]; ak.y = red[k][1];
            bk.x = red[k][2]; bk.y = red[k][3];
            ck.x = red[k][4]; ck.y = red[k][5];
            dk.x = red[k][6]; dk.y = red[k][7];
            v2f nb = ak * b + bk;
            v2f nc = ck * a + cS;
            v2f nd = (dS + dk) + ck * b;
            a = ak * a; b = nb; cS = nc; dS = nd;
            oacc += red[k][8];
        }
        float* pw = ws + WS_PART + (size_t)bid * 12;
        pw[0] = a.x;  pw[1] = b.x;  pw[2] = cS.x; pw[3] = dS.x;
        pw[4] = a.y;  pw[5] = b.y;  pw[6] = cS.y; pw[7] = dS.y;
        pw[8] = oacc;
        if (q == 0) { pw[9] = OCV0; pw[10] = I0; pw[11] = Rs; }
    }
}

// ---------------- kernel B: combine quarters + output ----------------
__global__ void __launch_bounds__(256) onenet_final(
    const float* __restrict__ ws, float* __restrict__ out)
{
    const int row = blockIdx.x * 256 + threadIdx.x;
    if (row >= NB) return;
    const float* p0 = ws + WS_PART + (size_t)row * 48;

    v2f a, b, cS, dS;
    a.x  = p0[0]; a.y  = p0[4];
    b.x  = p0[1]; b.y  = p0[5];
    cS.x = p0[2]; cS.y = p0[6];
    dS.x = p0[3]; dS.y = p0[7];
    float O = p0[8];
    float OCV0 = p0[9], I0 = p0[10], Rs = p0[11];
#pragma unroll
    for (int k = 1; k < 4; ++k) {
        const float* pk = p0 + k * 12;
        v2f ak, bk, ck, dk;
        ak.x = pk[0]; ak.y = pk[4];
        bk.x = pk[1]; bk.y = pk[5];
        ck.x = pk[2]; ck.y = pk[6];
        dk.x = pk[3]; dk.y = pk[7];
        v2f nb = ak * b + bk;
        v2f nc = ck * a + cS;
        v2f nd = (dS + dk) + ck * b;
        a = ak * a; b = nb; cS = nc; dS = nd;
        O += pk[8];
    }
    float U10 = -OCV0 - I0 * Rs;                 // U_H0 = 0
    float SH  = dS.x;                            // sum U_H/I
    float S1  = fmaf(cS.y, U10, dS.y);           // sum U_1/I
    out[row] = (O - SH - S1) * (1.0f / 4096.0f);
}

extern "C" void kernel_launch(void* const* d_in, const int* in_sizes, int n_in,
                              void* d_out, int out_size, void* d_ws, size_t ws_size,
                              hipStream_t stream) {
    const float* X   = (const float*)d_in[0];
    const float* SC  = (const float*)d_in[1];
    const float* pW1 = (const float*)d_in[2];
    const float* pb1 = (const float*)d_in[3];
    const float* pW2 = (const float*)d_in[4];
    const float* pb2 = (const float*)d_in[5];
    const float* rW1 = (const float*)d_in[6];
    const float* rb1 = (const float*)d_in[7];
    const float* rW2 = (const float*)d_in[8];
    const float* rb2 = (const float*)d_in[9];
    float* out = (float*)d_out;
    float* ws  = (float*)d_ws;

    onenet_main<<<NB * 4, TPB, 0, stream>>>(X, SC, pW1, pb1, pW2, pb2,
                                            rW1, rb1, rW2, rb2, ws);
    onenet_final<<<NB / 256, 256, 0, stream>>>(ws, out);
}